// Round 4
// baseline (6692.039 us; speedup 1.0000x reference)
//
#include <hip/hip_runtime.h>

// GIG_GAT: pheno GEMM + 3x GATConv (separable attention, segment-softmax by src,
// atomic scatter by dst) + output GEMM/argmax + gathers. All fp32.

#define LRELU_ATT(v) ((v) >= 0.f ? (v) : 0.2f * (v))

// Order-preserving float<->uint encoding for atomicMax on floats (incl. negatives).
__device__ __forceinline__ unsigned encf(float f) {
    unsigned u = __float_as_uint(f);
    return (u & 0x80000000u) ? ~u : (u | 0x80000000u);
}
__device__ __forceinline__ float decf(unsigned u) {
    return __uint_as_float((u & 0x80000000u) ? (u ^ 0x80000000u) : ~u);
}

// Y[N,128] = X[N,K] @ W[K,128] + b. 32 rows/block, 128 threads (1 col each).
// X tile staged in LDS; xs reads are wave-broadcast (conflict-free); W coalesced.
template <int K>
__global__ __launch_bounds__(128)
void gemm_n128(const float* __restrict__ X, const float* __restrict__ W,
               const float* __restrict__ bvec, float* __restrict__ Y, int N)
{
    __shared__ __align__(16) float xs[32][K];
    const int tid = threadIdx.x;
    const int r0  = blockIdx.x * 32;

    for (int idx = tid; idx < 32 * K; idx += 128) {
        int r = idx / K, c = idx - r * K;
        int gr = r0 + r;
        xs[r][c] = (gr < N) ? X[(size_t)gr * K + c] : 0.f;
    }
    __syncthreads();

    float acc[32];
#pragma unroll
    for (int r = 0; r < 32; ++r) acc[r] = 0.f;

    for (int k = 0; k < K; k += 4) {
        float w0 = W[(k + 0) * 128 + tid];
        float w1 = W[(k + 1) * 128 + tid];
        float w2 = W[(k + 2) * 128 + tid];
        float w3 = W[(k + 3) * 128 + tid];
#pragma unroll
        for (int r = 0; r < 32; ++r) {
            float4 xv = *reinterpret_cast<const float4*>(&xs[r][k]);
            acc[r] = fmaf(xv.x, w0, acc[r]);
            acc[r] = fmaf(xv.y, w1, acc[r]);
            acc[r] = fmaf(xv.z, w2, acc[r]);
            acc[r] = fmaf(xv.w, w3, acc[r]);
        }
    }
    const float b = bvec[tid];
    for (int r = 0; r < 32; ++r) {
        int gr = r0 + r;
        if (gr < N) Y[(size_t)gr * 128 + tid] = acc[r] + b;
    }
}

// Per node: a_i[n,h] = sum_k h[n,h*32+k]*att[h,k]; a_j uses att[h,32+k].
// Also inits OUT[n,:] = bias (scatter accumulator) and amax/denom.
// One wave (64 lanes) per node; 4 nodes per 256-thread block.
__global__ __launch_bounds__(256)
void node_dots_init(const float* __restrict__ H, const float* __restrict__ att,
                    const float* __restrict__ bias,
                    float* __restrict__ ai, float* __restrict__ aj,
                    unsigned* __restrict__ amax, float* __restrict__ denom,
                    float* __restrict__ OUT, int N)
{
    const int lane = threadIdx.x & 63;
    const int n    = blockIdx.x * 4 + (threadIdx.x >> 6);
    if (n >= N) return;

    const float v0 = H[(size_t)n * 128 + lane];
    const float v1 = H[(size_t)n * 128 + 64 + lane];
    const int hh = lane >> 5, k = lane & 31;   // v0 -> heads 0/1, v1 -> heads 2/3

    float si0 = v0 * att[hh * 64 + k];
    float sj0 = v0 * att[hh * 64 + 32 + k];
    float si1 = v1 * att[(2 + hh) * 64 + k];
    float sj1 = v1 * att[(2 + hh) * 64 + 32 + k];

#pragma unroll
    for (int m = 1; m < 32; m <<= 1) {   // reduce over k within each 32-lane half
        si0 += __shfl_xor(si0, m);
        sj0 += __shfl_xor(sj0, m);
        si1 += __shfl_xor(si1, m);
        sj1 += __shfl_xor(sj1, m);
    }

    OUT[(size_t)n * 128 + lane]      = bias[lane];
    OUT[(size_t)n * 128 + 64 + lane] = bias[64 + lane];

    if ((lane & 31) == 0) {
        const int hA = lane >> 5;                 // 0 (lane 0) or 1 (lane 32)
        ai[(size_t)n * 4 + hA]     = si0;
        aj[(size_t)n * 4 + hA]     = sj0;
        ai[(size_t)n * 4 + 2 + hA] = si1;
        aj[(size_t)n * 4 + 2 + hA] = sj1;
        if (lane == 0) {
#pragma unroll
            for (int h = 0; h < 4; ++h) {
                amax[(size_t)n * 4 + h]  = 0u;    // encoded "very small"
                denom[(size_t)n * 4 + h] = 0.f;
            }
        }
    }
}

__global__ __launch_bounds__(256)
void edge_max(const int* __restrict__ ei, int E, int N,
              const float* __restrict__ ai, const float* __restrict__ aj,
              unsigned* __restrict__ amax)
{
    const int e = blockIdx.x * 256 + threadIdx.x;
    if (e >= E + N) return;
    int s, d;
    if (e < E) { s = ei[e]; d = ei[E + e]; } else { s = d = e - E; }
    float4 vi = *reinterpret_cast<const float4*>(&ai[(size_t)d * 4]);
    float4 vj = *reinterpret_cast<const float4*>(&aj[(size_t)s * 4]);
    float a;
    a = vi.x + vj.x; a = LRELU_ATT(a); atomicMax(&amax[(size_t)s * 4 + 0], encf(a));
    a = vi.y + vj.y; a = LRELU_ATT(a); atomicMax(&amax[(size_t)s * 4 + 1], encf(a));
    a = vi.z + vj.z; a = LRELU_ATT(a); atomicMax(&amax[(size_t)s * 4 + 2], encf(a));
    a = vi.w + vj.w; a = LRELU_ATT(a); atomicMax(&amax[(size_t)s * 4 + 3], encf(a));
}

__global__ __launch_bounds__(256)
void edge_sum(const int* __restrict__ ei, int E, int N,
              const float* __restrict__ ai, const float* __restrict__ aj,
              const unsigned* __restrict__ amax, float* __restrict__ denom)
{
    const int e = blockIdx.x * 256 + threadIdx.x;
    if (e >= E + N) return;
    int s, d;
    if (e < E) { s = ei[e]; d = ei[E + e]; } else { s = d = e - E; }
    float4 vi = *reinterpret_cast<const float4*>(&ai[(size_t)d * 4]);
    float4 vj = *reinterpret_cast<const float4*>(&aj[(size_t)s * 4]);
#pragma unroll
    for (int h = 0; h < 4; ++h) {
        float a = ((const float*)&vi)[h] + ((const float*)&vj)[h];
        a = LRELU_ATT(a);
        float m  = decf(amax[(size_t)s * 4 + h]);
        float ex = expf(a - m);
        atomicAdd(&denom[(size_t)s * 4 + h], ex);
    }
}

// One wave per edge: lane L handles feature elements 2L, 2L+1 (head = L>>4).
// OUT[dst] += H[src] * coef.
__global__ __launch_bounds__(256)
void edge_scatter(const int* __restrict__ ei, int E, int N,
                  const float* __restrict__ ai, const float* __restrict__ aj,
                  const unsigned* __restrict__ amax, const float* __restrict__ denom,
                  const float* __restrict__ H, float* __restrict__ OUT)
{
    const int lane = threadIdx.x & 63;
    const int e    = blockIdx.x * 4 + (threadIdx.x >> 6);
    if (e >= E + N) return;
    int s, d;
    if (e < E) { s = ei[e]; d = ei[E + e]; } else { s = d = e - E; }

    const int h = lane >> 4;
    float a = ai[(size_t)d * 4 + h] + aj[(size_t)s * 4 + h];
    a = LRELU_ATT(a);
    float m    = decf(amax[(size_t)s * 4 + h]);
    float ex   = expf(a - m);
    float coef = ex / (denom[(size_t)s * 4 + h] + 1e-16f);

    float2 hv = *reinterpret_cast<const float2*>(&H[(size_t)s * 128 + lane * 2]);
    atomicAdd(&OUT[(size_t)d * 128 + lane * 2],     hv.x * coef);
    atomicAdd(&OUT[(size_t)d * 128 + lane * 2 + 1], hv.y * coef);
}

// relu in place (float4); optionally mirror to cp (x_embed output after layer 3).
__global__ __launch_bounds__(256)
void relu_kernel(float* __restrict__ P, float* __restrict__ cp, int n4)
{
    const int i = blockIdx.x * 256 + threadIdx.x;
    if (i >= n4) return;
    float4 v = reinterpret_cast<float4*>(P)[i];
    v.x = fmaxf(v.x, 0.f); v.y = fmaxf(v.y, 0.f);
    v.z = fmaxf(v.z, 0.f); v.w = fmaxf(v.w, 0.f);
    reinterpret_cast<float4*>(P)[i] = v;
    if (cp) reinterpret_cast<float4*>(cp)[i] = v;
}

// out3[n,:] = G[n,:] @ outW[128,3]; ypred = argmax (first occurrence, strict >).
__global__ __launch_bounds__(256)
void out_kernel(const float* __restrict__ G, const float* __restrict__ oW,
                float* __restrict__ out3, float* __restrict__ ypredF, int N)
{
    __shared__ float w[384];
    for (int i = threadIdx.x; i < 384; i += 256) w[i] = oW[i];
    __syncthreads();
    const int n = blockIdx.x * 256 + threadIdx.x;
    if (n >= N) return;
    const float* g = G + (size_t)n * 128;
    float a0 = 0.f, a1 = 0.f, a2 = 0.f;
    for (int k = 0; k < 128; k += 4) {
        float4 gv = *reinterpret_cast<const float4*>(&g[k]);
        a0 = fmaf(gv.x, w[(k+0)*3+0], a0); a1 = fmaf(gv.x, w[(k+0)*3+1], a1); a2 = fmaf(gv.x, w[(k+0)*3+2], a2);
        a0 = fmaf(gv.y, w[(k+1)*3+0], a0); a1 = fmaf(gv.y, w[(k+1)*3+1], a1); a2 = fmaf(gv.y, w[(k+1)*3+2], a2);
        a0 = fmaf(gv.z, w[(k+2)*3+0], a0); a1 = fmaf(gv.z, w[(k+2)*3+1], a1); a2 = fmaf(gv.z, w[(k+2)*3+2], a2);
        a0 = fmaf(gv.w, w[(k+3)*3+0], a0); a1 = fmaf(gv.w, w[(k+3)*3+1], a1); a2 = fmaf(gv.w, w[(k+3)*3+2], a2);
    }
    out3[(size_t)n * 3 + 0] = a0;
    out3[(size_t)n * 3 + 1] = a1;
    out3[(size_t)n * 3 + 2] = a2;
    int idx = 0; float best = a0;
    if (a1 > best) { best = a1; idx = 1; }
    if (a2 > best) { best = a2; idx = 2; }
    ypredF[n] = (float)idx;
}

__global__ __launch_bounds__(256)
void gather_kernel(const int* __restrict__ nix, const float* __restrict__ out3,
                   const float* __restrict__ ypredF, float* __restrict__ nodeOut,
                   float* __restrict__ ynode, int M)
{
    const int i = blockIdx.x * 256 + threadIdx.x;
    if (i >= M) return;
    const int n = nix[i];
    nodeOut[(size_t)i * 3 + 0] = out3[(size_t)n * 3 + 0];
    nodeOut[(size_t)i * 3 + 1] = out3[(size_t)n * 3 + 1];
    nodeOut[(size_t)i * 3 + 2] = out3[(size_t)n * 3 + 2];
    ynode[i] = ypredF[n];
}

extern "C" void kernel_launch(void* const* d_in, const int* in_sizes, int n_in,
                              void* d_out, int out_size, void* d_ws, size_t ws_size,
                              hipStream_t stream)
{
    const float* x      = (const float*)d_in[0];
    const int*   ei     = (const int*)d_in[1];
    const int*   nodeix = (const int*)d_in[2];
    const float* phW    = (const float*)d_in[3];
    const float* phb    = (const float*)d_in[4];
    const float* Wl[3]   = {(const float*)d_in[5],  (const float*)d_in[9],  (const float*)d_in[13]};
    const float* bl[3]   = {(const float*)d_in[6],  (const float*)d_in[10], (const float*)d_in[14]};
    const float* attl[3] = {(const float*)d_in[7],  (const float*)d_in[11], (const float*)d_in[15]};
    const float* bsl[3]  = {(const float*)d_in[8],  (const float*)d_in[12], (const float*)d_in[16]};
    const float* outW    = (const float*)d_in[17];

    const int N  = in_sizes[0] / 256;
    const int E  = in_sizes[1] / 2;
    const int M  = in_sizes[2];
    const int EN = E + N;

    // Workspace layout (floats): P[N*128] Q[N*128] ai[N*4] aj[N*4] amax[N*4] denom[N*4] out3[N*3]
    float*    P     = (float*)d_ws;
    float*    Q     = P + (size_t)N * 128;
    float*    ai    = Q + (size_t)N * 128;
    float*    aj    = ai + (size_t)N * 4;
    unsigned* amax  = (unsigned*)(aj + (size_t)N * 4);
    float*    denom = (float*)(amax + (size_t)N * 4);
    float*    out3  = denom + (size_t)N * 4;

    // d_out layout: x_embed[N*128] node_output[M*3] ypred[N] y_nodepred[M]
    float* o_embed   = (float*)d_out;
    float* o_nodeout = o_embed + (size_t)N * 128;
    float* o_ypred   = o_nodeout + (size_t)M * 3;
    float* o_ynode   = o_ypred + N;

    // pheno transform: P = x @ phW + phb
    gemm_n128<256><<<(N + 31) / 32, 128, 0, stream>>>(x, phW, phb, P, N);

    for (int l = 0; l < 3; ++l) {
        // h = P @ W + b  -> Q
        gemm_n128<128><<<(N + 31) / 32, 128, 0, stream>>>(P, Wl[l], bl[l], Q, N);
        // per-node attention dots; init P=bias, amax/denom
        node_dots_init<<<(N + 3) / 4, 256, 0, stream>>>(Q, attl[l], bsl[l], ai, aj, amax, denom, P, N);
        // segment softmax by src (two atomic passes), then scatter to dst
        edge_max<<<(EN + 255) / 256, 256, 0, stream>>>(ei, E, N, ai, aj, amax);
        edge_sum<<<(EN + 255) / 256, 256, 0, stream>>>(ei, E, N, ai, aj, amax, denom);
        edge_scatter<<<(EN + 3) / 4, 256, 0, stream>>>(ei, E, N, ai, aj, amax, denom, Q, P);
        // relu (leaky_relu(0.5) after relu is identity); layer 3 also writes x_embed
        relu_kernel<<<((N * 128 / 4) + 255) / 256, 256, 0, stream>>>(P, (l == 2) ? o_embed : nullptr, N * 128 / 4);
    }

    out_kernel<<<(N + 255) / 256, 256, 0, stream>>>(P, outW, out3, o_ypred, N);
    gather_kernel<<<(M + 255) / 256, 256, 0, stream>>>(nodeix, out3, o_ypred, o_nodeout, o_ynode, M);
}

// Round 6
// 2022.064 us; speedup vs baseline: 3.3095x; 3.3095x over previous
//
#include <hip/hip_runtime.h>
#include <math.h>

// GIG_GAT: pheno GEMM + 3x GATConv with CSR-gather aggregation (no feature atomics),
// CSR-gather segment softmax (no atomics), fused bias+relu epilogue. All fp32.
// CSR rows are canonicalized (sorted) after the atomic fill so every float
// accumulation runs in an identical order on every call (graph-replay tripwire).

#define LRELU_ATT(v) ((v) >= 0.f ? (v) : 0.2f * (v))

// ---------------- GEMM: Y[N,128] = X[N,K] @ W[K,128] + b ----------------
// 32 rows/block, 128 threads (1 col each). X tile in LDS; W coalesced from L2.
template <int K>
__global__ __launch_bounds__(128)
void gemm_n128(const float* __restrict__ X, const float* __restrict__ W,
               const float* __restrict__ bvec, float* __restrict__ Y, int N)
{
    __shared__ __align__(16) float xs[32][K];
    const int tid = threadIdx.x;
    const int r0  = blockIdx.x * 32;

    for (int idx = tid; idx < 32 * K; idx += 128) {
        int r = idx / K, c = idx - r * K;
        int gr = r0 + r;
        xs[r][c] = (gr < N) ? X[(size_t)gr * K + c] : 0.f;
    }
    __syncthreads();

    float acc[32];
#pragma unroll
    for (int r = 0; r < 32; ++r) acc[r] = 0.f;

    for (int k = 0; k < K; k += 4) {
        float w0 = W[(k + 0) * 128 + tid];
        float w1 = W[(k + 1) * 128 + tid];
        float w2 = W[(k + 2) * 128 + tid];
        float w3 = W[(k + 3) * 128 + tid];
#pragma unroll
        for (int r = 0; r < 32; ++r) {
            float4 xv = *reinterpret_cast<const float4*>(&xs[r][k]);
            acc[r] = fmaf(xv.x, w0, acc[r]);
            acc[r] = fmaf(xv.y, w1, acc[r]);
            acc[r] = fmaf(xv.z, w2, acc[r]);
            acc[r] = fmaf(xv.w, w3, acc[r]);
        }
    }
    const float b = bvec[tid];
    for (int r = 0; r < 32; ++r) {
        int gr = r0 + r;
        if (gr < N) Y[(size_t)gr * 128 + tid] = acc[r] + b;
    }
}

// ---------------- per-node attention dot products ----------------
// ai[n,h] = sum_k H[n,h*32+k]*att[h,k]; aj[n,h] = sum_k H[n,h*32+k]*att[h,32+k]
__global__ __launch_bounds__(256)
void node_dots(const float* __restrict__ H, const float* __restrict__ att,
               float* __restrict__ ai, float* __restrict__ aj, int N)
{
    const int lane = threadIdx.x & 63;
    const int n    = blockIdx.x * 4 + (threadIdx.x >> 6);
    if (n >= N) return;

    const float v0 = H[(size_t)n * 128 + lane];
    const float v1 = H[(size_t)n * 128 + 64 + lane];
    const int hh = lane >> 5, k = lane & 31;   // v0 -> heads 0/1, v1 -> heads 2/3

    float si0 = v0 * att[hh * 64 + k];
    float sj0 = v0 * att[hh * 64 + 32 + k];
    float si1 = v1 * att[(2 + hh) * 64 + k];
    float sj1 = v1 * att[(2 + hh) * 64 + 32 + k];

#pragma unroll
    for (int m = 1; m < 32; m <<= 1) {
        si0 += __shfl_xor(si0, m);
        sj0 += __shfl_xor(sj0, m);
        si1 += __shfl_xor(si1, m);
        sj1 += __shfl_xor(sj1, m);
    }
    if ((lane & 31) == 0) {
        const int hA = lane >> 5;
        ai[(size_t)n * 4 + hA]     = si0;
        aj[(size_t)n * 4 + hA]     = sj0;
        ai[(size_t)n * 4 + 2 + hA] = si1;
        aj[(size_t)n * 4 + 2 + hA] = sj1;
    }
}

// ---------------- CSR build ----------------
__global__ __launch_bounds__(256)
void count_deg(const int* __restrict__ ei, int E, int N,
               int* __restrict__ cnt_s, int* __restrict__ cnt_d)
{
    const int e = blockIdx.x * 256 + threadIdx.x;
    if (e >= E + N) return;
    int s, d;
    if (e < E) { s = ei[e]; d = ei[E + e]; } else { s = d = e - E; }
    atomicAdd(&cnt_s[s], 1);
    atomicAdd(&cnt_d[d], 1);
}

__global__ __launch_bounds__(256)
void scan_part(const int* __restrict__ cnt, int* __restrict__ bsum, int n)
{
    __shared__ int sm[256];
    const int i = blockIdx.x * 256 + threadIdx.x;
    sm[threadIdx.x] = (i < n) ? cnt[i] : 0;
    __syncthreads();
    for (int s = 128; s > 0; s >>= 1) {
        if (threadIdx.x < s) sm[threadIdx.x] += sm[threadIdx.x + s];
        __syncthreads();
    }
    if (threadIdx.x == 0) bsum[blockIdx.x] = sm[0];
}

__global__ __launch_bounds__(1024)
void scan_bsums(int* __restrict__ bsum, int nb)
{
    __shared__ int sm[1024];
    const int i = threadIdx.x;
    if (i < nb) sm[i] = bsum[i];
    __syncthreads();
    if (i == 0) {
        int run = 0;
        for (int t = 0; t < nb; ++t) { int v = sm[t]; sm[t] = run; run += v; }
    }
    __syncthreads();
    if (i < nb) bsum[i] = sm[i];
}

__global__ __launch_bounds__(256)
void scan_final(const int* __restrict__ cnt, const int* __restrict__ bsum,
                int* __restrict__ row, int n)
{
    const int i = blockIdx.x * 256 + threadIdx.x;
    const int lane = threadIdx.x & 63, wid = threadIdx.x >> 6;
    int v = (i < n) ? cnt[i] : 0;
    int inc = v;
#pragma unroll
    for (int d = 1; d < 64; d <<= 1) {
        int y = __shfl_up(inc, d);
        if (lane >= d) inc += y;
    }
    __shared__ int wsum[4];
    if (lane == 63) wsum[wid] = inc;
    __syncthreads();
    int wofs = 0;
    for (int w = 0; w < wid; ++w) wofs += wsum[w];
    if (i < n) row[i] = inc - v + wofs + bsum[blockIdx.x];
}

__global__ __launch_bounds__(256)
void fill_csr(const int* __restrict__ ei, int E, int N,
              const int* __restrict__ row_s, const int* __restrict__ row_d,
              int* __restrict__ fc_s, int* __restrict__ fc_d,
              int* __restrict__ ent_s, int* __restrict__ ent_d)
{
    const int e = blockIdx.x * 256 + threadIdx.x;
    if (e >= E + N) return;
    int s, d;
    if (e < E) { s = ei[e]; d = ei[E + e]; } else { s = d = e - E; }
    int p = atomicAdd(&fc_s[s], 1); ent_s[row_s[s] + p] = d;
    int q = atomicAdd(&fc_d[d], 1); ent_d[row_d[d] + q] = s;
}

// Canonicalize: sort each row's neighbor list ascending (one thread per node,
// in-place insertion sort; rows are small, data is L2/L3-resident). Makes the
// CSR — and therefore every downstream float accumulation order — deterministic
// regardless of the atomic fill order. Duplicate values are indistinguishable.
__global__ __launch_bounds__(256)
void sort_rows(const int* __restrict__ row, int* __restrict__ ent, int N, int EN)
{
    const int n = blockIdx.x * 256 + threadIdx.x;
    if (n >= N) return;
    const int lo = row[n];
    const int hi = (n == N - 1) ? EN : row[n + 1];
    for (int i = lo + 1; i < hi; ++i) {
        int v = ent[i];
        int j = i - 1;
        while (j >= lo && ent[j] > v) { ent[j + 1] = ent[j]; --j; }
        ent[j + 1] = v;
    }
}

// ---------------- segment softmax grouped by src (gather, no atomics) ----------------
// One wave per src node: lane = slot(0..15) x head(0..3). Two passes (max, sum).
__global__ __launch_bounds__(256)
void softmax_src(const int* __restrict__ row_s, const int* __restrict__ ent_s,
                 const float* __restrict__ ai, const float* __restrict__ aj,
                 float* __restrict__ amaxF, float* __restrict__ rden,
                 int N, int EN)
{
    const int lane = threadIdx.x & 63;
    const int n    = blockIdx.x * 4 + (threadIdx.x >> 6);
    if (n >= N) return;
    const int row = row_s[n];
    const int end = (n == N - 1) ? EN : row_s[n + 1];
    const int slot = lane & 15, h = lane >> 4;
    const float ajh = aj[(size_t)n * 4 + h];

    float m = -INFINITY;
    for (int t = row + slot; t < end; t += 16) {
        const int d = ent_s[t];
        const float a = LRELU_ATT(ai[(size_t)d * 4 + h] + ajh);
        m = fmaxf(m, a);
    }
#pragma unroll
    for (int mm = 1; mm < 16; mm <<= 1) m = fmaxf(m, __shfl_xor(m, mm));

    float ssum = 0.f;
    for (int t = row + slot; t < end; t += 16) {
        const int d = ent_s[t];
        const float a = LRELU_ATT(ai[(size_t)d * 4 + h] + ajh);
        ssum += __expf(a - m);
    }
#pragma unroll
    for (int mm = 1; mm < 16; mm <<= 1) ssum += __shfl_xor(ssum, mm);

    if (slot == 0) {
        amaxF[(size_t)n * 4 + h] = m;
        rden[(size_t)n * 4 + h]  = 1.f / (ssum + 1e-16f);
    }
}

// ---------------- aggregation by dst (gather, no atomics), fused bias+relu ----------------
// One wave per dst node; lane handles feature elems 2L, 2L+1 (head = L>>4).
__global__ __launch_bounds__(256)
void aggregate_dst(const int* __restrict__ row_d, const int* __restrict__ ent_d,
                   const float* __restrict__ ai, const float* __restrict__ aj,
                   const float* __restrict__ amaxF, const float* __restrict__ rden,
                   const float* __restrict__ H, const float* __restrict__ bias,
                   float* __restrict__ OUT, int N, int EN)
{
    const int lane = threadIdx.x & 63;
    const int n    = blockIdx.x * 4 + (threadIdx.x >> 6);
    if (n >= N) return;
    const int row = row_d[n];
    const int end = (n == N - 1) ? EN : row_d[n + 1];
    const int h   = lane >> 4;
    const float aih = ai[(size_t)n * 4 + h];

    float accx = 0.f, accy = 0.f;
    for (int t = row; t < end; ++t) {
        const int s = ent_d[t];
        const float a    = LRELU_ATT(aih + aj[(size_t)s * 4 + h]);
        const float coef = __expf(a - amaxF[(size_t)s * 4 + h]) * rden[(size_t)s * 4 + h];
        const float2 hv  = *reinterpret_cast<const float2*>(&H[(size_t)s * 128 + lane * 2]);
        accx = fmaf(hv.x, coef, accx);
        accy = fmaf(hv.y, coef, accy);
    }
    const float2 bv = *reinterpret_cast<const float2*>(&bias[lane * 2]);
    OUT[(size_t)n * 128 + lane * 2]     = fmaxf(accx + bv.x, 0.f);
    OUT[(size_t)n * 128 + lane * 2 + 1] = fmaxf(accy + bv.y, 0.f);
}

// ---------------- output head ----------------
__global__ __launch_bounds__(256)
void out_kernel(const float* __restrict__ G, const float* __restrict__ oW,
                float* __restrict__ out3, float* __restrict__ ypredF, int N)
{
    __shared__ float w[384];
    for (int i = threadIdx.x; i < 384; i += 256) w[i] = oW[i];
    __syncthreads();
    const int n = blockIdx.x * 256 + threadIdx.x;
    if (n >= N) return;
    const float* g = G + (size_t)n * 128;
    float a0 = 0.f, a1 = 0.f, a2 = 0.f;
    for (int k = 0; k < 128; k += 4) {
        float4 gv = *reinterpret_cast<const float4*>(&g[k]);
        a0 = fmaf(gv.x, w[(k+0)*3+0], a0); a1 = fmaf(gv.x, w[(k+0)*3+1], a1); a2 = fmaf(gv.x, w[(k+0)*3+2], a2);
        a0 = fmaf(gv.y, w[(k+1)*3+0], a0); a1 = fmaf(gv.y, w[(k+1)*3+1], a1); a2 = fmaf(gv.y, w[(k+1)*3+2], a2);
        a0 = fmaf(gv.z, w[(k+2)*3+0], a0); a1 = fmaf(gv.z, w[(k+2)*3+1], a1); a2 = fmaf(gv.z, w[(k+2)*3+2], a2);
        a0 = fmaf(gv.w, w[(k+3)*3+0], a0); a1 = fmaf(gv.w, w[(k+3)*3+1], a1); a2 = fmaf(gv.w, w[(k+3)*3+2], a2);
    }
    out3[(size_t)n * 3 + 0] = a0;
    out3[(size_t)n * 3 + 1] = a1;
    out3[(size_t)n * 3 + 2] = a2;
    int idx = 0; float best = a0;
    if (a1 > best) { best = a1; idx = 1; }
    if (a2 > best) { best = a2; idx = 2; }
    ypredF[n] = (float)idx;
}

__global__ __launch_bounds__(256)
void gather_kernel(const int* __restrict__ nix, const float* __restrict__ out3,
                   const float* __restrict__ ypredF, float* __restrict__ nodeOut,
                   float* __restrict__ ynode, int M)
{
    const int i = blockIdx.x * 256 + threadIdx.x;
    if (i >= M) return;
    const int n = nix[i];
    nodeOut[(size_t)i * 3 + 0] = out3[(size_t)n * 3 + 0];
    nodeOut[(size_t)i * 3 + 1] = out3[(size_t)n * 3 + 1];
    nodeOut[(size_t)i * 3 + 2] = out3[(size_t)n * 3 + 2];
    ynode[i] = ypredF[n];
}

extern "C" void kernel_launch(void* const* d_in, const int* in_sizes, int n_in,
                              void* d_out, int out_size, void* d_ws, size_t ws_size,
                              hipStream_t stream)
{
    const float* x      = (const float*)d_in[0];
    const int*   ei     = (const int*)d_in[1];
    const int*   nodeix = (const int*)d_in[2];
    const float* phW    = (const float*)d_in[3];
    const float* phb    = (const float*)d_in[4];
    const float* Wl[3]   = {(const float*)d_in[5],  (const float*)d_in[9],  (const float*)d_in[13]};
    const float* bl[3]   = {(const float*)d_in[6],  (const float*)d_in[10], (const float*)d_in[14]};
    const float* attl[3] = {(const float*)d_in[7],  (const float*)d_in[11], (const float*)d_in[15]};
    const float* bsl[3]  = {(const float*)d_in[8],  (const float*)d_in[12], (const float*)d_in[16]};
    const float* outW    = (const float*)d_in[17];

    const int N  = in_sizes[0] / 256;
    const int E  = in_sizes[1] / 2;
    const int M  = in_sizes[2];
    const int EN = E + N;

    // ---- workspace layout ----
    float* P     = (float*)d_ws;                    // N*128
    float* Q     = P + (size_t)N * 128;             // N*128
    float* ai    = Q + (size_t)N * 128;             // N*4
    float* aj    = ai + (size_t)N * 4;              // N*4
    float* amaxF = aj + (size_t)N * 4;              // N*4
    float* rden  = amaxF + (size_t)N * 4;           // N*4
    float* out3  = rden + (size_t)N * 4;            // N*3
    int* row_s   = (int*)(out3 + (size_t)N * 3);    // N
    int* row_d   = row_s + N;                       // N
    int* cnt_s   = row_d + N;                       // N (histogram, reused as fill ctr)
    int* cnt_d   = cnt_s + N;                       // N
    int* bsum_s  = cnt_d + N;                       // 1024
    int* bsum_d  = bsum_s + 1024;                   // 1024
    int* ent_s   = bsum_d + 1024;                   // EN
    int* ent_d   = ent_s + (size_t)EN;              // EN

    // ---- d_out layout: x_embed[N*128] node_output[M*3] ypred[N] y_nodepred[M]
    float* o_embed   = (float*)d_out;
    float* o_nodeout = o_embed + (size_t)N * 128;
    float* o_ypred   = o_nodeout + (size_t)M * 3;
    float* o_ynode   = o_ypred + N;

    const int nb = (N + 255) / 256;

    // ---- CSR build (once; reused by all 3 layers) ----
    hipMemsetAsync(cnt_s, 0, (size_t)2 * N * sizeof(int), stream);
    count_deg<<<(EN + 255) / 256, 256, 0, stream>>>(ei, E, N, cnt_s, cnt_d);
    scan_part<<<nb, 256, 0, stream>>>(cnt_s, bsum_s, N);
    scan_part<<<nb, 256, 0, stream>>>(cnt_d, bsum_d, N);
    scan_bsums<<<1, 1024, 0, stream>>>(bsum_s, nb);
    scan_bsums<<<1, 1024, 0, stream>>>(bsum_d, nb);
    scan_final<<<nb, 256, 0, stream>>>(cnt_s, bsum_s, row_s, N);
    scan_final<<<nb, 256, 0, stream>>>(cnt_d, bsum_d, row_d, N);
    hipMemsetAsync(cnt_s, 0, (size_t)2 * N * sizeof(int), stream);
    fill_csr<<<(EN + 255) / 256, 256, 0, stream>>>(ei, E, N, row_s, row_d, cnt_s, cnt_d, ent_s, ent_d);
    // canonicalize row order -> deterministic float accumulation on every call
    sort_rows<<<nb, 256, 0, stream>>>(row_s, ent_s, N, EN);
    sort_rows<<<nb, 256, 0, stream>>>(row_d, ent_d, N, EN);

    // ---- pheno transform: P = x @ phW + phb ----
    gemm_n128<256><<<(N + 31) / 32, 128, 0, stream>>>(x, phW, phb, P, N);

    // ---- 3 GAT layers ----
    for (int l = 0; l < 3; ++l) {
        float* tgt = (l == 2) ? o_embed : P;   // layer 3 writes x_embed directly
        gemm_n128<128><<<(N + 31) / 32, 128, 0, stream>>>(P, Wl[l], bl[l], Q, N);
        node_dots<<<(N + 3) / 4, 256, 0, stream>>>(Q, attl[l], ai, aj, N);
        softmax_src<<<(N + 3) / 4, 256, 0, stream>>>(row_s, ent_s, ai, aj, amaxF, rden, N, EN);
        aggregate_dst<<<(N + 3) / 4, 256, 0, stream>>>(row_d, ent_d, ai, aj, amaxF, rden,
                                                       Q, bsl[l], tgt, N, EN);
    }

    out_kernel<<<(N + 255) / 256, 256, 0, stream>>>(o_embed, outW, out3, o_ypred, N);
    gather_kernel<<<(M + 255) / 256, 256, 0, stream>>>(nodeix, out3, o_ypred, o_nodeout, o_ynode, M);
}

// Round 7
// 1684.085 us; speedup vs baseline: 3.9737x; 1.2007x over previous
//
#include <hip/hip_runtime.h>
#include <math.h>

// GIG_GAT: pheno GEMM + 3x GATConv with CSR-gather aggregation (no feature atomics),
// CSR-gather segment softmax (no atomics), fused bias+relu epilogue. All fp32.
// CSR rows are canonicalized (sorted) after the atomic fill so every float
// accumulation runs in an identical order on every call (graph-replay tripwire).
// GEMM: 128x128 tile / 256 threads / 8x8 register blocking, Xt+W staged in LDS.

#define LRELU_ATT(v) ((v) >= 0.f ? (v) : 0.2f * (v))

// ---------------- GEMM: Y[N,128] = X[N,K] @ W[K,128] + b ----------------
// Block: 256 threads = 16(tx) x 16(ty); thread tile 8x8 (rows 8ty.., cols 8tx..).
// Per k-step: 4 ds_read_b128 feed 64 FMAs (16:1) -> VALU-bound, not LDS-bound.
template <int K>
__global__ __launch_bounds__(256)
void gemm_tile(const float* __restrict__ X, const float* __restrict__ W,
               const float* __restrict__ bvec, float* __restrict__ Y, int N)
{
    __shared__ __align__(16) float xt[32][132];   // [k][row], padded stride
    __shared__ __align__(16) float ws[32][132];   // [k][col], padded stride

    const int t  = threadIdx.x;
    const int tx = t & 15, ty = t >> 4;
    const int r0 = blockIdx.x * 128;

    float acc[8][8];
#pragma unroll
    for (int i = 0; i < 8; ++i)
#pragma unroll
        for (int j = 0; j < 8; ++j) acc[i][j] = 0.f;

    const int srow = t >> 3;          // X stage: 32 rows per pass
    const int sk4  = (t & 7) * 4;
    const int wkr  = t >> 5;          // W stage: 8 k-rows per pass
    const int wc4  = (t & 31) * 4;

    for (int kc = 0; kc < K; kc += 32) {
        // stage X^T (transposed: xt[k][row]), zero-fill rows >= N
#pragma unroll
        for (int p = 0; p < 4; ++p) {
            const int r  = srow + p * 32;
            const int gr = r0 + r;
            float4 v = make_float4(0.f, 0.f, 0.f, 0.f);
            if (gr < N) v = *reinterpret_cast<const float4*>(&X[(size_t)gr * K + kc + sk4]);
            xt[sk4 + 0][r] = v.x; xt[sk4 + 1][r] = v.y;
            xt[sk4 + 2][r] = v.z; xt[sk4 + 3][r] = v.w;
        }
        // stage W rows kc..kc+31 (row-major, coalesced)
#pragma unroll
        for (int p = 0; p < 4; ++p) {
            const int k = wkr + p * 8;
            float4 v = *reinterpret_cast<const float4*>(&W[(size_t)(kc + k) * 128 + wc4]);
            *reinterpret_cast<float4*>(&ws[k][wc4]) = v;
        }
        __syncthreads();

#pragma unroll
        for (int k = 0; k < 32; ++k) {
            const float4 a0 = *reinterpret_cast<const float4*>(&xt[k][8 * ty]);
            const float4 a1 = *reinterpret_cast<const float4*>(&xt[k][8 * ty + 4]);
            const float4 b0 = *reinterpret_cast<const float4*>(&ws[k][8 * tx]);
            const float4 b1 = *reinterpret_cast<const float4*>(&ws[k][8 * tx + 4]);
            const float av[8] = {a0.x, a0.y, a0.z, a0.w, a1.x, a1.y, a1.z, a1.w};
            const float bv[8] = {b0.x, b0.y, b0.z, b0.w, b1.x, b1.y, b1.z, b1.w};
#pragma unroll
            for (int i = 0; i < 8; ++i)
#pragma unroll
                for (int j = 0; j < 8; ++j)
                    acc[i][j] = fmaf(av[i], bv[j], acc[i][j]);
        }
        __syncthreads();
    }

    const float4 bb0 = *reinterpret_cast<const float4*>(&bvec[8 * tx]);
    const float4 bb1 = *reinterpret_cast<const float4*>(&bvec[8 * tx + 4]);
#pragma unroll
    for (int i = 0; i < 8; ++i) {
        const int gr = r0 + 8 * ty + i;
        if (gr < N) {
            float4 o0 = make_float4(acc[i][0] + bb0.x, acc[i][1] + bb0.y,
                                    acc[i][2] + bb0.z, acc[i][3] + bb0.w);
            float4 o1 = make_float4(acc[i][4] + bb1.x, acc[i][5] + bb1.y,
                                    acc[i][6] + bb1.z, acc[i][7] + bb1.w);
            *reinterpret_cast<float4*>(&Y[(size_t)gr * 128 + 8 * tx])     = o0;
            *reinterpret_cast<float4*>(&Y[(size_t)gr * 128 + 8 * tx + 4]) = o1;
        }
    }
}

// ---------------- per-node attention dot products ----------------
// ai[n,h] = sum_k H[n,h*32+k]*att[h,k]; aj[n,h] = sum_k H[n,h*32+k]*att[h,32+k]
__global__ __launch_bounds__(256)
void node_dots(const float* __restrict__ H, const float* __restrict__ att,
               float* __restrict__ ai, float* __restrict__ aj, int N)
{
    const int lane = threadIdx.x & 63;
    const int n    = blockIdx.x * 4 + (threadIdx.x >> 6);
    if (n >= N) return;

    const float v0 = H[(size_t)n * 128 + lane];
    const float v1 = H[(size_t)n * 128 + 64 + lane];
    const int hh = lane >> 5, k = lane & 31;   // v0 -> heads 0/1, v1 -> heads 2/3

    float si0 = v0 * att[hh * 64 + k];
    float sj0 = v0 * att[hh * 64 + 32 + k];
    float si1 = v1 * att[(2 + hh) * 64 + k];
    float sj1 = v1 * att[(2 + hh) * 64 + 32 + k];

#pragma unroll
    for (int m = 1; m < 32; m <<= 1) {
        si0 += __shfl_xor(si0, m);
        sj0 += __shfl_xor(sj0, m);
        si1 += __shfl_xor(si1, m);
        sj1 += __shfl_xor(sj1, m);
    }
    if ((lane & 31) == 0) {
        const int hA = lane >> 5;
        ai[(size_t)n * 4 + hA]     = si0;
        aj[(size_t)n * 4 + hA]     = sj0;
        ai[(size_t)n * 4 + 2 + hA] = si1;
        aj[(size_t)n * 4 + 2 + hA] = sj1;
    }
}

// ---------------- CSR build ----------------
__global__ __launch_bounds__(256)
void count_deg(const int* __restrict__ ei, int E, int N,
               int* __restrict__ cnt_s, int* __restrict__ cnt_d)
{
    const int e = blockIdx.x * 256 + threadIdx.x;
    if (e >= E + N) return;
    int s, d;
    if (e < E) { s = ei[e]; d = ei[E + e]; } else { s = d = e - E; }
    atomicAdd(&cnt_s[s], 1);
    atomicAdd(&cnt_d[d], 1);
}

__global__ __launch_bounds__(256)
void scan_part(const int* __restrict__ cnt, int* __restrict__ bsum, int n)
{
    __shared__ int sm[256];
    const int i = blockIdx.x * 256 + threadIdx.x;
    sm[threadIdx.x] = (i < n) ? cnt[i] : 0;
    __syncthreads();
    for (int s = 128; s > 0; s >>= 1) {
        if (threadIdx.x < s) sm[threadIdx.x] += sm[threadIdx.x + s];
        __syncthreads();
    }
    if (threadIdx.x == 0) bsum[blockIdx.x] = sm[0];
}

__global__ __launch_bounds__(1024)
void scan_bsums(int* __restrict__ bsum, int nb)
{
    __shared__ int sm[1024];
    const int i = threadIdx.x;
    if (i < nb) sm[i] = bsum[i];
    __syncthreads();
    if (i == 0) {
        int run = 0;
        for (int t = 0; t < nb; ++t) { int v = sm[t]; sm[t] = run; run += v; }
    }
    __syncthreads();
    if (i < nb) bsum[i] = sm[i];
}

__global__ __launch_bounds__(256)
void scan_final(const int* __restrict__ cnt, const int* __restrict__ bsum,
                int* __restrict__ row, int n)
{
    const int i = blockIdx.x * 256 + threadIdx.x;
    const int lane = threadIdx.x & 63, wid = threadIdx.x >> 6;
    int v = (i < n) ? cnt[i] : 0;
    int inc = v;
#pragma unroll
    for (int d = 1; d < 64; d <<= 1) {
        int y = __shfl_up(inc, d);
        if (lane >= d) inc += y;
    }
    __shared__ int wsum[4];
    if (lane == 63) wsum[wid] = inc;
    __syncthreads();
    int wofs = 0;
    for (int w = 0; w < wid; ++w) wofs += wsum[w];
    if (i < n) row[i] = inc - v + wofs + bsum[blockIdx.x];
}

__global__ __launch_bounds__(256)
void fill_csr(const int* __restrict__ ei, int E, int N,
              const int* __restrict__ row_s, const int* __restrict__ row_d,
              int* __restrict__ fc_s, int* __restrict__ fc_d,
              int* __restrict__ ent_s, int* __restrict__ ent_d)
{
    const int e = blockIdx.x * 256 + threadIdx.x;
    if (e >= E + N) return;
    int s, d;
    if (e < E) { s = ei[e]; d = ei[E + e]; } else { s = d = e - E; }
    int p = atomicAdd(&fc_s[s], 1); ent_s[row_s[s] + p] = d;
    int q = atomicAdd(&fc_d[d], 1); ent_d[row_d[d] + q] = s;
}

// Canonicalize: sort each row's neighbor list ascending (one thread per node).
// Makes the CSR — and every downstream float accumulation order — deterministic
// regardless of atomic fill order (graph-replay tripwire).
__global__ __launch_bounds__(256)
void sort_rows(const int* __restrict__ row, int* __restrict__ ent, int N, int EN)
{
    const int n = blockIdx.x * 256 + threadIdx.x;
    if (n >= N) return;
    const int lo = row[n];
    const int hi = (n == N - 1) ? EN : row[n + 1];
    for (int i = lo + 1; i < hi; ++i) {
        int v = ent[i];
        int j = i - 1;
        while (j >= lo && ent[j] > v) { ent[j + 1] = ent[j]; --j; }
        ent[j + 1] = v;
    }
}

// ---------------- segment softmax grouped by src (gather, no atomics) ----------------
__global__ __launch_bounds__(256)
void softmax_src(const int* __restrict__ row_s, const int* __restrict__ ent_s,
                 const float* __restrict__ ai, const float* __restrict__ aj,
                 float* __restrict__ amaxF, float* __restrict__ rden,
                 int N, int EN)
{
    const int lane = threadIdx.x & 63;
    const int n    = blockIdx.x * 4 + (threadIdx.x >> 6);
    if (n >= N) return;
    const int row = row_s[n];
    const int end = (n == N - 1) ? EN : row_s[n + 1];
    const int slot = lane & 15, h = lane >> 4;
    const float ajh = aj[(size_t)n * 4 + h];

    float m = -INFINITY;
    for (int t = row + slot; t < end; t += 16) {
        const int d = ent_s[t];
        const float a = LRELU_ATT(ai[(size_t)d * 4 + h] + ajh);
        m = fmaxf(m, a);
    }
#pragma unroll
    for (int mm = 1; mm < 16; mm <<= 1) m = fmaxf(m, __shfl_xor(m, mm));

    float ssum = 0.f;
    for (int t = row + slot; t < end; t += 16) {
        const int d = ent_s[t];
        const float a = LRELU_ATT(ai[(size_t)d * 4 + h] + ajh);
        ssum += __expf(a - m);
    }
#pragma unroll
    for (int mm = 1; mm < 16; mm <<= 1) ssum += __shfl_xor(ssum, mm);

    if (slot == 0) {
        amaxF[(size_t)n * 4 + h] = m;
        rden[(size_t)n * 4 + h]  = 1.f / (ssum + 1e-16f);
    }
}

// ---------------- aggregation by dst (gather, no atomics), fused bias+relu ----------------
__global__ __launch_bounds__(256)
void aggregate_dst(const int* __restrict__ row_d, const int* __restrict__ ent_d,
                   const float* __restrict__ ai, const float* __restrict__ aj,
                   const float* __restrict__ amaxF, const float* __restrict__ rden,
                   const float* __restrict__ H, const float* __restrict__ bias,
                   float* __restrict__ OUT, int N, int EN)
{
    const int lane = threadIdx.x & 63;
    const int n    = blockIdx.x * 4 + (threadIdx.x >> 6);
    if (n >= N) return;
    const int row = row_d[n];
    const int end = (n == N - 1) ? EN : row_d[n + 1];
    const int h   = lane >> 4;
    const float aih = ai[(size_t)n * 4 + h];

    float accx = 0.f, accy = 0.f;
    for (int t = row; t < end; ++t) {
        const int s = ent_d[t];
        const float a    = LRELU_ATT(aih + aj[(size_t)s * 4 + h]);
        const float coef = __expf(a - amaxF[(size_t)s * 4 + h]) * rden[(size_t)s * 4 + h];
        const float2 hv  = *reinterpret_cast<const float2*>(&H[(size_t)s * 128 + lane * 2]);
        accx = fmaf(hv.x, coef, accx);
        accy = fmaf(hv.y, coef, accy);
    }
    const float2 bv = *reinterpret_cast<const float2*>(&bias[lane * 2]);
    OUT[(size_t)n * 128 + lane * 2]     = fmaxf(accx + bv.x, 0.f);
    OUT[(size_t)n * 128 + lane * 2 + 1] = fmaxf(accy + bv.y, 0.f);
}

// ---------------- output head ----------------
__global__ __launch_bounds__(256)
void out_kernel(const float* __restrict__ G, const float* __restrict__ oW,
                float* __restrict__ out3, float* __restrict__ ypredF, int N)
{
    __shared__ float w[384];
    for (int i = threadIdx.x; i < 384; i += 256) w[i] = oW[i];
    __syncthreads();
    const int n = blockIdx.x * 256 + threadIdx.x;
    if (n >= N) return;
    const float* g = G + (size_t)n * 128;
    float a0 = 0.f, a1 = 0.f, a2 = 0.f;
    for (int k = 0; k < 128; k += 4) {
        float4 gv = *reinterpret_cast<const float4*>(&g[k]);
        a0 = fmaf(gv.x, w[(k+0)*3+0], a0); a1 = fmaf(gv.x, w[(k+0)*3+1], a1); a2 = fmaf(gv.x, w[(k+0)*3+2], a2);
        a0 = fmaf(gv.y, w[(k+1)*3+0], a0); a1 = fmaf(gv.y, w[(k+1)*3+1], a1); a2 = fmaf(gv.y, w[(k+1)*3+2], a2);
        a0 = fmaf(gv.z, w[(k+2)*3+0], a0); a1 = fmaf(gv.z, w[(k+2)*3+1], a1); a2 = fmaf(gv.z, w[(k+2)*3+2], a2);
        a0 = fmaf(gv.w, w[(k+3)*3+0], a0); a1 = fmaf(gv.w, w[(k+3)*3+1], a1); a2 = fmaf(gv.w, w[(k+3)*3+2], a2);
    }
    out3[(size_t)n * 3 + 0] = a0;
    out3[(size_t)n * 3 + 1] = a1;
    out3[(size_t)n * 3 + 2] = a2;
    int idx = 0; float best = a0;
    if (a1 > best) { best = a1; idx = 1; }
    if (a2 > best) { best = a2; idx = 2; }
    ypredF[n] = (float)idx;
}

__global__ __launch_bounds__(256)
void gather_kernel(const int* __restrict__ nix, const float* __restrict__ out3,
                   const float* __restrict__ ypredF, float* __restrict__ nodeOut,
                   float* __restrict__ ynode, int M)
{
    const int i = blockIdx.x * 256 + threadIdx.x;
    if (i >= M) return;
    const int n = nix[i];
    nodeOut[(size_t)i * 3 + 0] = out3[(size_t)n * 3 + 0];
    nodeOut[(size_t)i * 3 + 1] = out3[(size_t)n * 3 + 1];
    nodeOut[(size_t)i * 3 + 2] = out3[(size_t)n * 3 + 2];
    ynode[i] = ypredF[n];
}

extern "C" void kernel_launch(void* const* d_in, const int* in_sizes, int n_in,
                              void* d_out, int out_size, void* d_ws, size_t ws_size,
                              hipStream_t stream)
{
    const float* x      = (const float*)d_in[0];
    const int*   ei     = (const int*)d_in[1];
    const int*   nodeix = (const int*)d_in[2];
    const float* phW    = (const float*)d_in[3];
    const float* phb    = (const float*)d_in[4];
    const float* Wl[3]   = {(const float*)d_in[5],  (const float*)d_in[9],  (const float*)d_in[13]};
    const float* bl[3]   = {(const float*)d_in[6],  (const float*)d_in[10], (const float*)d_in[14]};
    const float* attl[3] = {(const float*)d_in[7],  (const float*)d_in[11], (const float*)d_in[15]};
    const float* bsl[3]  = {(const float*)d_in[8],  (const float*)d_in[12], (const float*)d_in[16]};
    const float* outW    = (const float*)d_in[17];

    const int N  = in_sizes[0] / 256;
    const int E  = in_sizes[1] / 2;
    const int M  = in_sizes[2];
    const int EN = E + N;

    // ---- workspace layout ----
    float* P     = (float*)d_ws;                    // N*128
    float* Q     = P + (size_t)N * 128;             // N*128
    float* ai    = Q + (size_t)N * 128;             // N*4
    float* aj    = ai + (size_t)N * 4;              // N*4
    float* amaxF = aj + (size_t)N * 4;              // N*4
    float* rden  = amaxF + (size_t)N * 4;           // N*4
    float* out3  = rden + (size_t)N * 4;            // N*3
    int* row_s   = (int*)(out3 + (size_t)N * 3);    // N
    int* row_d   = row_s + N;                       // N
    int* cnt_s   = row_d + N;                       // N (histogram, reused as fill ctr)
    int* cnt_d   = cnt_s + N;                       // N
    int* bsum_s  = cnt_d + N;                       // 1024
    int* bsum_d  = bsum_s + 1024;                   // 1024
    int* ent_s   = bsum_d + 1024;                   // EN
    int* ent_d   = ent_s + (size_t)EN;              // EN

    // ---- d_out layout: x_embed[N*128] node_output[M*3] ypred[N] y_nodepred[M]
    float* o_embed   = (float*)d_out;
    float* o_nodeout = o_embed + (size_t)N * 128;
    float* o_ypred   = o_nodeout + (size_t)M * 3;
    float* o_ynode   = o_ypred + N;

    const int nb = (N + 255) / 256;
    const int ng = (N + 127) / 128;   // GEMM grid

    // ---- CSR build (once; reused by all 3 layers) ----
    hipMemsetAsync(cnt_s, 0, (size_t)2 * N * sizeof(int), stream);
    count_deg<<<(EN + 255) / 256, 256, 0, stream>>>(ei, E, N, cnt_s, cnt_d);
    scan_part<<<nb, 256, 0, stream>>>(cnt_s, bsum_s, N);
    scan_part<<<nb, 256, 0, stream>>>(cnt_d, bsum_d, N);
    scan_bsums<<<1, 1024, 0, stream>>>(bsum_s, nb);
    scan_bsums<<<1, 1024, 0, stream>>>(bsum_d, nb);
    scan_final<<<nb, 256, 0, stream>>>(cnt_s, bsum_s, row_s, N);
    scan_final<<<nb, 256, 0, stream>>>(cnt_d, bsum_d, row_d, N);
    hipMemsetAsync(cnt_s, 0, (size_t)2 * N * sizeof(int), stream);
    fill_csr<<<(EN + 255) / 256, 256, 0, stream>>>(ei, E, N, row_s, row_d, cnt_s, cnt_d, ent_s, ent_d);
    // canonicalize row order -> deterministic float accumulation on every call
    sort_rows<<<nb, 256, 0, stream>>>(row_s, ent_s, N, EN);
    sort_rows<<<nb, 256, 0, stream>>>(row_d, ent_d, N, EN);

    // ---- pheno transform: P = x @ phW + phb ----
    gemm_tile<256><<<ng, 256, 0, stream>>>(x, phW, phb, P, N);

    // ---- 3 GAT layers ----
    for (int l = 0; l < 3; ++l) {
        float* tgt = (l == 2) ? o_embed : P;   // layer 3 writes x_embed directly
        gemm_tile<128><<<ng, 256, 0, stream>>>(P, Wl[l], bl[l], Q, N);
        node_dots<<<(N + 3) / 4, 256, 0, stream>>>(Q, attl[l], ai, aj, N);
        softmax_src<<<(N + 3) / 4, 256, 0, stream>>>(row_s, ent_s, ai, aj, amaxF, rden, N, EN);
        aggregate_dst<<<(N + 3) / 4, 256, 0, stream>>>(row_d, ent_d, ai, aj, amaxF, rden,
                                                       Q, bsl[l], tgt, N, EN);
    }

    out_kernel<<<(N + 255) / 256, 256, 0, stream>>>(o_embed, outW, out3, o_ypred, N);
    gather_kernel<<<(M + 255) / 256, 256, 0, stream>>>(nodeix, out3, o_ypred, o_nodeout, o_ynode, M);
}